// Round 1
// baseline (1239.092 us; speedup 1.0000x reference)
//
#include <hip/hip_runtime.h>
#include <math.h>

// MotionGRU: B=4, N=4096, K=16, HID=128, FEAT=128
// ws layout: H0t f32 [4][4096][128] at 0 (8 MB), nn_idx int [4][4096][16] at 8 MB.

#define BIGV 1e30f

__device__ __forceinline__ float sigmoidf_(float x) { return 1.0f / (1.0f + __expf(-x)); }

// ---------------- transpose H0 [B,128,4096] -> H0t [B,4096,128] ----------------
__global__ __launch_bounds__(256) void k_transpose(const float* __restrict__ H0,
                                                   float* __restrict__ H0t) {
  __shared__ float tile[16][17];
  int blk = blockIdx.x;
  int b = blk >> 11;            // 2048 blocks per batch: 8 c-tiles x 256 n-tiles
  int rem = blk & 2047;
  int c0 = (rem >> 8) << 4;
  int n0 = (rem & 255) << 4;
  int tr = threadIdx.x >> 4, tc = threadIdx.x & 15;
  tile[tr][tc] = H0[((b << 7) + c0 + tr) * 4096 + n0 + tc];
  __syncthreads();
  H0t[((b << 12) + n0 + tr) * 128 + c0 + tc] = tile[tc][tr];
}

// ---------------- exact KNN: one wave per query ----------------
__global__ __launch_bounds__(256) void k_knn(const float* __restrict__ p0,
                                             const float* __restrict__ p1,
                                             int* __restrict__ nn) {
  int wv = threadIdx.x >> 6, lane = threadIdx.x & 63;
  int g = (blockIdx.x << 2) + wv;   // query id in [0, 16384)
  int b = g >> 12, m = g & 4095;
  const float* P0 = p0 + b * 3 * 4096;
  const float* P1 = p1 + b * 3 * 4096;
  float x1 = P1[m], y1 = P1[4096 + m], z1 = P1[8192 + m];
  float s1 = x1 * x1 + y1 * y1 + z1 * z1;

  float d[64];
  float v0 = BIGV, v1 = BIGV, v2 = BIGV, v3 = BIGV;
  int j0 = 0, j1 = 0, j2 = 0, j3 = 0;
#pragma unroll
  for (int t = 0; t < 64; ++t) {
    int j = (t << 6) + lane;
    float x0 = P0[j], y0 = P0[4096 + j], z0 = P0[8192 + j];
    float s0 = x0 * x0 + y0 * y0 + z0 * z0;
    float dt = x1 * x0 + y1 * y0 + z1 * z0;
    float sq = s1 + s0 - 2.0f * dt;   // same formula as reference
    d[t] = sq;
    // stable sorted-insert into per-lane top-4 (strict < matches jax tie order)
    bool c0_ = sq < v0, c1_ = sq < v1, c2_ = sq < v2, c3_ = sq < v3;
    v3 = c3_ ? (c2_ ? v2 : sq) : v3; j3 = c3_ ? (c2_ ? j2 : j) : j3;
    v2 = c2_ ? (c1_ ? v1 : sq) : v2; j2 = c2_ ? (c1_ ? j1 : j) : j2;
    v1 = c1_ ? (c0_ ? v0 : sq) : v1; j1 = c1_ ? (c0_ ? j0 : j) : j1;
    v0 = c0_ ? sq : v0;              j0 = c0_ ? j : j0;
  }

  int ob = ((b << 12) + m) << 4;
  bool fb = false;                 // fallback mode (a lane exhausted its top-4)
  float lastv = -BIGV; int lastj = -1;
#pragma unroll 1
  for (int r = 0; r < 16; ++r) {
    float mv; int mj;
    if (!fb) {
      mv = v0; mj = j0;
    } else {
      // exact threshold rescan: smallest (d, j) lexicographically > (lastv, lastj)
      mv = BIGV; mj = 0x7fffffff;
#pragma unroll
      for (int t = 0; t < 64; ++t) {
        int j = (t << 6) + lane;
        float dv = d[t];
        bool gt = (dv > lastv) || (dv == lastv && j > lastj);
        bool lt = gt && ((dv < mv) || (dv == mv && j < mj));
        mv = lt ? dv : mv; mj = lt ? j : mj;
      }
    }
    // wave argmin, ties -> lower index (matches top_k stability)
#pragma unroll
    for (int off = 1; off < 64; off <<= 1) {
      float ov = __shfl_xor(mv, off);
      int oj = __shfl_xor(mj, off);
      bool tk = (ov < mv) || (ov == mv && oj < mj);
      mv = tk ? ov : mv; mj = tk ? oj : mj;
    }
    if (lane == 0) nn[ob + r] = mj;
    lastv = mv; lastj = mj;
    if (!fb) {
      bool win = (j0 == mj);
      if (win) { v0 = v1; j0 = j1; v1 = v2; j1 = j2; v2 = v3; j2 = j3; v3 = BIGV; j3 = 0x7fffffff; }
      fb = __any(v0 >= BIGV);
    }
  }
}

// ---------------- fused main kernel ----------------
// LDS carve (floats):
constexpr int SM_XH = 0;                    // Xh  [128 pq][136]  (i: 0..127 H0, 128..130 rela, 131 dist)
constexpr int SM_W  = 128 * 136;            // Wt  [132][132] transposed weight tile
constexpr int SM_FE = SM_W + 132 * 132;     // Fe  [8][128] feats
constexpr int SM_PR = SM_FE + 1024;         // Pr  [8][128] gateR*H1_0
constexpr int SM_OL = SM_PR + 1024;         // Ol  [128][12] output staging
constexpr int SM_IX = SM_OL + 128 * 12;     // Ix  int[128]
constexpr int SM_FLOATS = SM_IX + 128;
constexpr int SMEM_BYTES = SM_FLOATS * 4;   // 154176 B

__device__ __forceinline__ void stage_w_main(const float* __restrict__ W, int stride,
                                             float* __restrict__ Wt, int t) {
  // dest i 0..127 <- src col 4+i (H0 part); dest i 128..131 <- src col i-128 (rela/dist)
#pragma unroll
  for (int it = 0; it < 64; ++it) {
    int k = (it << 8) + t;
    int row = k >> 7, i = k & 127;
    Wt[i * 132 + row] = W[row * stride + 4 + i];
  }
#pragma unroll
  for (int it = 0; it < 2; ++it) {
    int k = (it << 8) + t;      // 0..511
    int row = k >> 2, ii = k & 3;
    Wt[(128 + ii) * 132 + row] = W[row * stride + ii];
  }
}

__device__ __forceinline__ void stage_w_epi(const float* __restrict__ W, int stride, int coloff,
                                            float* __restrict__ Wt, int t) {
#pragma unroll
  for (int it = 0; it < 64; ++it) {
    int k = (it << 8) + t;
    int row = k >> 7, c = k & 127;
    Wt[c * 132 + row] = W[row * stride + coloff + c];
  }
}

__device__ __forceinline__ void compute_mat(const float* __restrict__ Wt,
                                            const float* __restrict__ Xh,
                                            int r4, int p, float rmax[4]) {
  float acc[4][16];
#pragma unroll
  for (int rr = 0; rr < 4; ++rr)
#pragma unroll
    for (int q = 0; q < 16; ++q) acc[rr][q] = 0.0f;
  const float* xb = Xh + (p << 4) * 136;
#pragma unroll 1
  for (int i0 = 0; i0 < 33; ++i0) {
    float w[4][4];
#pragma unroll
    for (int ii = 0; ii < 4; ++ii) {
      float4 wv = *(const float4*)&Wt[((i0 << 2) + ii) * 132 + (r4 << 2)];
      w[ii][0] = wv.x; w[ii][1] = wv.y; w[ii][2] = wv.z; w[ii][3] = wv.w;
    }
#pragma unroll
    for (int q = 0; q < 16; ++q) {
      float4 x = *(const float4*)&xb[q * 136 + (i0 << 2)];
#pragma unroll
      for (int rr = 0; rr < 4; ++rr) {
        acc[rr][q] = fmaf(w[0][rr], x.x, acc[rr][q]);
        acc[rr][q] = fmaf(w[1][rr], x.y, acc[rr][q]);
        acc[rr][q] = fmaf(w[2][rr], x.z, acc[rr][q]);
        acc[rr][q] = fmaf(w[3][rr], x.w, acc[rr][q]);
      }
    }
  }
#pragma unroll
  for (int rr = 0; rr < 4; ++rr) {
    float m = acc[rr][0];
#pragma unroll
    for (int q = 1; q < 16; ++q) m = fmaxf(m, acc[rr][q]);
    rmax[rr] = m;
  }
}

__device__ __forceinline__ void dot_epi(const float* __restrict__ Wt,
                                        const float* __restrict__ xv,
                                        int r4, float f[4]) {
#pragma unroll
  for (int rr = 0; rr < 4; ++rr) f[rr] = 0.0f;
#pragma unroll 1
  for (int c0 = 0; c0 < 32; ++c0) {
    float w[4][4];
#pragma unroll
    for (int cc = 0; cc < 4; ++cc) {
      float4 wv = *(const float4*)&Wt[((c0 << 2) + cc) * 132 + (r4 << 2)];
      w[cc][0] = wv.x; w[cc][1] = wv.y; w[cc][2] = wv.z; w[cc][3] = wv.w;
    }
    float4 x = *(const float4*)&xv[c0 << 2];
#pragma unroll
    for (int rr = 0; rr < 4; ++rr) {
      f[rr] = fmaf(w[0][rr], x.x, f[rr]);
      f[rr] = fmaf(w[1][rr], x.y, f[rr]);
      f[rr] = fmaf(w[2][rr], x.z, f[rr]);
      f[rr] = fmaf(w[3][rr], x.w, f[rr]);
    }
  }
}

__global__ __launch_bounds__(256, 1) void k_main(
    const float* __restrict__ H0t, const int* __restrict__ nn,
    const float* __restrict__ p0, const float* __restrict__ p1,
    const float* __restrict__ ct, const float* __restrict__ mo,
    const float* __restrict__ W_R, const float* __restrict__ b_R,
    const float* __restrict__ W_Z, const float* __restrict__ b_Z,
    const float* __restrict__ W_H0, const float* __restrict__ b_H0,
    const float* __restrict__ W_H1, const float* __restrict__ b_H1,
    float* __restrict__ out) {
  extern __shared__ float smem[];
  float* Xh = smem + SM_XH;
  float* Wt = smem + SM_W;
  float* Fe = smem + SM_FE;
  float* Pr = smem + SM_PR;
  float* Ol = smem + SM_OL;
  int* Ix = (int*)(smem + SM_IX);

  int t = threadIdx.x;
  int blk = blockIdx.x;
  int b = blk >> 9;              // 512 blocks per batch, 8 points each
  int n0 = (blk & 511) << 3;

  if (t < 128) Ix[t] = nn[((b << 12) + n0 + (t >> 4)) * 16 + (t & 15)];
  __syncthreads();

  // gather neighbor H0 rows into Xh[pq][0..127] (coalesced 512B rows from H0t)
  {
    int g = t >> 4, li = t & 15;
#pragma unroll
    for (int it = 0; it < 8; ++it) {
      int pq = (it << 4) + g;
      int row = Ix[pq];
      const float4* src = (const float4*)&H0t[((b << 12) + row) * 128 + (li << 3)];
      float4 a0 = src[0], a1 = src[1];
      float4* dst = (float4*)&Xh[pq * 136 + (li << 3)];
      dst[0] = a0; dst[1] = a1;
    }
  }
  // rela / dist -> Xh[pq][128..131]
  if (t < 128) {
    int p = t >> 4;
    int j = Ix[t];
    int n = n0 + p;
    const float* P1b = p1 + b * 3 * 4096;
    const float* P0b = p0 + b * 3 * 4096;
    float x1 = P1b[n], y1 = P1b[4096 + n], z1 = P1b[8192 + n];
    float x0 = P0b[j], y0 = P0b[4096 + j], z0 = P0b[8192 + j];
    float rx = x0 - x1, ry = y0 - y1, rz = z0 - z1;
    float dist = sqrtf(rx * rx + ry * ry + rz * rz);
    *(float4*)&Xh[t * 136 + 128] = make_float4(rx, ry, rz, dist);
  }
  // feats = [contents; motions] for the 8 points
  {
    int p = t >> 5, c4 = (t & 31) << 2;
    int n = n0 + p;
    const float* srcb = (c4 < 64) ? (ct + (b * 64) * 4096) : (mo + (b * 64) * 4096);
    int cbase = (c4 < 64) ? c4 : (c4 - 64);
    float f0 = srcb[(cbase + 0) * 4096 + n];
    float f1 = srcb[(cbase + 1) * 4096 + n];
    float f2 = srcb[(cbase + 2) * 4096 + n];
    float f3 = srcb[(cbase + 3) * 4096 + n];
    *(float4*)&Fe[(p << 7) + c4] = make_float4(f0, f1, f2, f3);
  }
  __syncthreads();

  int r4 = t & 31, p = t >> 5;   // rows 4*r4..4*r4+3, point p
  float rmR[4], rmZ[4], rmH[4];

  stage_w_main(W_R, 260, Wt, t);  __syncthreads();
  compute_mat(Wt, Xh, r4, p, rmR); __syncthreads();
  stage_w_main(W_Z, 260, Wt, t);  __syncthreads();
  compute_mat(Wt, Xh, r4, p, rmZ); __syncthreads();
  stage_w_main(W_H0, 132, Wt, t); __syncthreads();
  compute_mat(Wt, Xh, r4, p, rmH); __syncthreads();

  float fR[4], fZ[4], fA[4], hB[4];
  stage_w_epi(W_R, 260, 132, Wt, t); __syncthreads();
  dot_epi(Wt, Fe + (p << 7), r4, fR); __syncthreads();
  stage_w_epi(W_Z, 260, 132, Wt, t); __syncthreads();
  dot_epi(Wt, Fe + (p << 7), r4, fZ); __syncthreads();
  stage_w_epi(W_H1, 256, 0, Wt, t);  __syncthreads();
  dot_epi(Wt, Fe + (p << 7), r4, fA); __syncthreads();

  float gR[4], gZ[4], h0v[4];
#pragma unroll
  for (int rr = 0; rr < 4; ++rr) {
    int row = (r4 << 2) + rr;
    gR[rr] = sigmoidf_(rmR[rr] + fR[rr] + b_R[row]);
    gZ[rr] = sigmoidf_(rmZ[rr] + fZ[rr] + b_Z[row]);
    h0v[rr] = rmH[rr] + b_H0[row];
    Pr[(p << 7) + row] = gR[rr] * h0v[rr];
  }
  __syncthreads();
  stage_w_epi(W_H1, 256, 128, Wt, t); __syncthreads();
  dot_epi(Wt, Pr + (p << 7), r4, hB);
#pragma unroll
  for (int rr = 0; rr < 4; ++rr) {
    int row = (r4 << 2) + rr;
    float h1 = tanhf(fA[rr] + hB[rr] + b_H1[row]);
    float o = gZ[rr] * h0v[rr] + (1.0f - gZ[rr]) * h1;
    Ol[row * 12 + p] = o;
  }
  __syncthreads();
  // coalesced store: 2 threads per row, float4 each
  {
    int row = t >> 1, ph = (t & 1) << 2;
    float4 v = *(const float4*)&Ol[row * 12 + ph];
    *(float4*)&out[((b << 7) + row) * 4096 + n0 + ph] = v;
  }
}

extern "C" void kernel_launch(void* const* d_in, const int* in_sizes, int n_in,
                              void* d_out, int out_size, void* d_ws, size_t ws_size,
                              hipStream_t stream) {
  const float* H0  = (const float*)d_in[0];
  const float* p0  = (const float*)d_in[1];
  const float* p1  = (const float*)d_in[2];
  const float* ct  = (const float*)d_in[3];
  const float* mo  = (const float*)d_in[4];
  const float* W_R = (const float*)d_in[5];
  const float* b_R = (const float*)d_in[6];
  const float* W_Z = (const float*)d_in[7];
  const float* b_Z = (const float*)d_in[8];
  const float* W_H0 = (const float*)d_in[9];
  const float* b_H0 = (const float*)d_in[10];
  const float* W_H1 = (const float*)d_in[11];
  const float* b_H1 = (const float*)d_in[12];
  float* out = (float*)d_out;

  float* H0t = (float*)d_ws;
  int* nn = (int*)((char*)d_ws + 8ull * 1024 * 1024);

  k_transpose<<<8192, 256, 0, stream>>>(H0, H0t);
  k_knn<<<4096, 256, 0, stream>>>(p0, p1, nn);
  hipFuncSetAttribute((const void*)k_main, hipFuncAttributeMaxDynamicSharedMemorySize, SMEM_BYTES);
  k_main<<<2048, 256, SMEM_BYTES, stream>>>(H0t, nn, p0, p1, ct, mo,
                                            W_R, b_R, W_Z, b_Z, W_H0, b_H0, W_H1, b_H1, out);
}

// Round 2
// 471.399 us; speedup vs baseline: 2.6285x; 2.6285x over previous
//
#include <hip/hip_runtime.h>
#include <math.h>

// MotionGRU: B=4, N=4096, K=16, HID=128, FEAT=128
// ws layout (bytes):
//   H0tb bf16 [4][4096][128]      @ 0        (4 MB)
//   nn    int [4][4096][16]       @ 4 MB     (1 MB)
//   WmainP bf16 frags 12T*9ks*64l*8 @ 5 MB   (110592 B)
//   WfeP   bf16 frags 12T*8ks*64l*8 @ 5.5 MB (98304 B)
//   SmG   f32 [16384][512]        @ 8 MB     (32 MB)   cols: [R 0-127 | Z 128-255 | H0 256-383 | H1a 384-511]

#define BIGV 1e30f

typedef __attribute__((ext_vector_type(8))) short bf16x8;
typedef __attribute__((ext_vector_type(16))) float f32x16;

#define MFMA32(a, b, c) __builtin_amdgcn_mfma_f32_32x32x16_bf16(a, b, c, 0, 0, 0)

__device__ __forceinline__ unsigned short f2bf(float x) {
  unsigned int u = __float_as_uint(x);
  unsigned int r = u + 0x7fffu + ((u >> 16) & 1u);
  return (unsigned short)(r >> 16);
}

// ---------------- transpose H0 [B,128,4096] -> H0tb bf16 [B,4096,128] ----------------
__global__ __launch_bounds__(256) void k_transpose(const float* __restrict__ H0,
                                                   unsigned short* __restrict__ H0tb) {
  __shared__ float tile[16][17];
  int blk = blockIdx.x;
  int b = blk >> 11;
  int rem = blk & 2047;
  int c0 = (rem >> 8) << 4;
  int n0 = (rem & 255) << 4;
  int tr = threadIdx.x >> 4, tc = threadIdx.x & 15;
  tile[tr][tc] = H0[((b << 7) + c0 + tr) * 4096 + n0 + tc];
  __syncthreads();
  H0tb[((b << 12) + n0 + tr) * 128 + c0 + tc] = f2bf(tile[tc][tr]);
}

// ---------------- exact KNN: one wave per query (validated round 1) ----------------
__global__ __launch_bounds__(256) void k_knn(const float* __restrict__ p0,
                                             const float* __restrict__ p1,
                                             int* __restrict__ nn) {
  int wv = threadIdx.x >> 6, lane = threadIdx.x & 63;
  int g = (blockIdx.x << 2) + wv;
  int b = g >> 12, m = g & 4095;
  const float* P0 = p0 + b * 3 * 4096;
  const float* P1 = p1 + b * 3 * 4096;
  float x1 = P1[m], y1 = P1[4096 + m], z1 = P1[8192 + m];
  float s1 = x1 * x1 + y1 * y1 + z1 * z1;

  float d[64];
  float v0 = BIGV, v1 = BIGV, v2 = BIGV, v3 = BIGV;
  int j0 = 0, j1 = 0, j2 = 0, j3 = 0;
#pragma unroll
  for (int t = 0; t < 64; ++t) {
    int j = (t << 6) + lane;
    float x0 = P0[j], y0 = P0[4096 + j], z0 = P0[8192 + j];
    float s0 = x0 * x0 + y0 * y0 + z0 * z0;
    float dt = x1 * x0 + y1 * y0 + z1 * z0;
    float sq = s1 + s0 - 2.0f * dt;
    d[t] = sq;
    bool c0_ = sq < v0, c1_ = sq < v1, c2_ = sq < v2, c3_ = sq < v3;
    v3 = c3_ ? (c2_ ? v2 : sq) : v3; j3 = c3_ ? (c2_ ? j2 : j) : j3;
    v2 = c2_ ? (c1_ ? v1 : sq) : v2; j2 = c2_ ? (c1_ ? j1 : j) : j2;
    v1 = c1_ ? (c0_ ? v0 : sq) : v1; j1 = c1_ ? (c0_ ? j0 : j) : j1;
    v0 = c0_ ? sq : v0;              j0 = c0_ ? j : j0;
  }

  int ob = ((b << 12) + m) << 4;
  bool fb = false;
  float lastv = -BIGV; int lastj = -1;
#pragma unroll 1
  for (int r = 0; r < 16; ++r) {
    float mv; int mj;
    if (!fb) {
      mv = v0; mj = j0;
    } else {
      mv = BIGV; mj = 0x7fffffff;
#pragma unroll
      for (int t = 0; t < 64; ++t) {
        int j = (t << 6) + lane;
        float dv = d[t];
        bool gt = (dv > lastv) || (dv == lastv && j > lastj);
        bool lt = gt && ((dv < mv) || (dv == mv && j < mj));
        mv = lt ? dv : mv; mj = lt ? j : mj;
      }
    }
#pragma unroll
    for (int off = 1; off < 64; off <<= 1) {
      float ov = __shfl_xor(mv, off);
      int oj = __shfl_xor(mj, off);
      bool tk = (ov < mv) || (ov == mv && oj < mj);
      mv = tk ? ov : mv; mj = tk ? oj : mj;
    }
    if (lane == 0) nn[ob + r] = mj;
    lastv = mv; lastj = mj;
    if (!fb) {
      bool win = (j0 == mj);
      if (win) { v0 = v1; j0 = j1; v1 = v2; j1 = j2; v2 = v3; j2 = j3; v3 = BIGV; j3 = 0x7fffffff; }
      fb = __any(v0 >= BIGV);
    }
  }
}

// ---------------- pack weight fragments (one-time, tiny) ----------------
// WmainP: logical Wmain[col 0..383][k 0..143], col<128:W_R row col; <256:W_Z; else W_H0.
//   k<128 -> W[row][4+k]; 128..131 -> W[row][k-128]; >=132 -> 0.
// frag lane l, elem i of (tile T, ks): col = 32T+(l&31), k = 16ks + 8*(l>>5) + i.
// WfeP: logical Wfe[col 0..511][k 0..127]; tiles 0-7 = cols 0-255 (R,Z feats part),
//   tiles 8-11 = H1a (W_H1[:, 0:128]) rows 32(t-8)..
__global__ __launch_bounds__(256) void k_prep(const float* __restrict__ W_R,
                                              const float* __restrict__ W_Z,
                                              const float* __restrict__ W_H0,
                                              const float* __restrict__ W_H1,
                                              unsigned short* __restrict__ WmainP,
                                              unsigned short* __restrict__ WfeP) {
  int t = blockIdx.x * 256 + threadIdx.x;
  if (t < 6912) {  // 12 tiles * 9 ks * 64 lanes
    int l = t & 63;
    int f = t >> 6;
    int ks = f % 9, T = f / 9;
    int col = T * 32 + (l & 31);
    int kb = ks * 16 + ((l >> 5) << 3);
    const float* W; int stride, row;
    if (col < 128)      { W = W_R;  stride = 260; row = col; }
    else if (col < 256) { W = W_Z;  stride = 260; row = col - 128; }
    else                { W = W_H0; stride = 132; row = col - 256; }
    unsigned int u[4];
#pragma unroll
    for (int i2 = 0; i2 < 4; ++i2) {
      float a0, a1;
      int k0 = kb + 2 * i2, k1 = k0 + 1;
      a0 = (k0 < 128) ? W[row * stride + 4 + k0] : ((k0 < 132) ? W[row * stride + (k0 - 128)] : 0.f);
      a1 = (k1 < 128) ? W[row * stride + 4 + k1] : ((k1 < 132) ? W[row * stride + (k1 - 128)] : 0.f);
      u[i2] = (unsigned int)f2bf(a0) | ((unsigned int)f2bf(a1) << 16);
    }
    uint4 pk; pk.x = u[0]; pk.y = u[1]; pk.z = u[2]; pk.w = u[3];
    *(uint4*)&WmainP[t * 8] = pk;
  } else if (t < 13056) {  // 12 tiles * 8 ks * 64 lanes
    int idx = t - 6912;
    int l = idx & 63;
    int ks = (idx >> 6) & 7;
    int tid = idx >> 9;
    int kb = ks * 16 + ((l >> 5) << 3);
    unsigned int u[4];
#pragma unroll
    for (int i2 = 0; i2 < 4; ++i2) {
      int k0 = kb + 2 * i2, k1 = k0 + 1;
      float a0, a1;
      if (tid < 8) {
        int col = tid * 32 + (l & 31);
        const float* W = (col < 128) ? W_R : W_Z;
        int row = (col < 128) ? col : col - 128;
        a0 = W[row * 260 + 132 + k0];
        a1 = W[row * 260 + 132 + k1];
      } else {
        int row = (tid - 8) * 32 + (l & 31);
        a0 = W_H1[row * 256 + k0];
        a1 = W_H1[row * 256 + k1];
      }
      u[i2] = (unsigned int)f2bf(a0) | ((unsigned int)f2bf(a1) << 16);
    }
    uint4 pk; pk.x = u[0]; pk.y = u[1]; pk.z = u[2]; pk.w = u[3];
    *(uint4*)&WfeP[idx * 8] = pk;
  }
}

// ---------------- main MFMA kernel: neighbor GEMM + max + feats GEMM ----------------
// block = 256 thr = 4 waves; group = 32 points (pairs: point a = n0+pi, point b = n0+16+pi).
// wave w owns output cols 96w..96w+95 (3 tiles) + H1a cols 384+32w..+31.
__global__ __launch_bounds__(256, 2) void k_mainmax(
    const unsigned short* __restrict__ H0tb, const int* __restrict__ nn,
    const float* __restrict__ p0, const float* __restrict__ p1,
    const float* __restrict__ ct, const float* __restrict__ mo,
    const short* __restrict__ WmainP, const short* __restrict__ WfeP,
    float* __restrict__ SmG) {
  __shared__ unsigned short Xb[2][18][32][8];   // [buf][kgroup][slot][8 bf16]
  __shared__ unsigned short FeL[16][32][8];     // feats A-frags [kgroup][pt][8]

  const int t = threadIdx.x;
  const int g = blockIdx.x;
  const int b = g >> 7;
  const int n0 = (g & 127) << 5;
  const int w = t >> 6, lane = t & 63;
  const int l31 = lane & 31, h = lane >> 5;

  // persistent Wmain B-frags: wave w tiles T = 3w..3w+2, 9 k-steps each (108 VGPRs)
  bf16x8 wfm[3][9];
#pragma unroll
  for (int tt = 0; tt < 3; ++tt)
#pragma unroll
    for (int ks = 0; ks < 9; ++ks)
      wfm[tt][ks] = *(const bf16x8*)&WmainP[(((3 * w + tt) * 9 + ks) * 64 + lane) * 8];

  // ---- staging helper: X for pair pi into Xb[buf]
  auto stageX = [&](int buf, int pi) {
    int s = t >> 3, c = t & 7;
    int n = n0 + pi + ((s >> 4) << 4);
    int j = nn[(((b << 12) + n) << 4) + (s & 15)];
    const uint4* src = (const uint4*)&H0tb[((b << 12) + j) * 128];
    *(uint4*)&Xb[buf][c][s][0]     = src[c];
    *(uint4*)&Xb[buf][c + 8][s][0] = src[c + 8];
    if (t < 32) {
      int s2 = t;
      int n2 = n0 + pi + ((s2 >> 4) << 4);
      int j2 = nn[(((b << 12) + n2) << 4) + (s2 & 15)];
      const float* P1b = p1 + b * 3 * 4096;
      const float* P0b = p0 + b * 3 * 4096;
      float rx = P0b[j2] - P1b[n2];
      float ry = P0b[4096 + j2] - P1b[4096 + n2];
      float rz = P0b[8192 + j2] - P1b[8192 + n2];
      float dd = sqrtf(rx * rx + ry * ry + rz * rz);
      uint4 pk;
      pk.x = (unsigned int)f2bf(rx) | ((unsigned int)f2bf(ry) << 16);
      pk.y = (unsigned int)f2bf(rz) | ((unsigned int)f2bf(dd) << 16);
      pk.z = 0u; pk.w = 0u;
      *(uint4*)&Xb[buf][16][s2][0] = pk;
      uint4 z; z.x = 0u; z.y = 0u; z.z = 0u; z.w = 0u;
      *(uint4*)&Xb[buf][17][s2][0] = z;
    }
  };

  // ---- stage feats A-frags (once per group) + X for pair 0
  {
    int s = t >> 3, kg = t & 7;
    int n = n0 + s;
#pragma unroll
    for (int half = 0; half < 2; ++half) {
      int kgg = kg + 8 * half;
      const float* src = half ? (mo + b * 64 * 4096) : (ct + b * 64 * 4096);
      int ch = kg * 8;
      unsigned int u[4];
#pragma unroll
      for (int i2 = 0; i2 < 4; ++i2) {
        float a0 = src[(ch + 2 * i2) * 4096 + n];
        float a1 = src[(ch + 2 * i2 + 1) * 4096 + n];
        u[i2] = (unsigned int)f2bf(a0) | ((unsigned int)f2bf(a1) << 16);
      }
      uint4 pk; pk.x = u[0]; pk.y = u[1]; pk.z = u[2]; pk.w = u[3];
      *(uint4*)&FeL[kgg][s][0] = pk;
    }
  }
  stageX(0, 0);
  __syncthreads();

  // ---- feats GEMM into accF (R/Z cols only; H0 cols stay 0)
  float accF[3][16];
#pragma unroll
  for (int tt = 0; tt < 3; ++tt)
#pragma unroll
    for (int r = 0; r < 16; ++r) accF[tt][r] = 0.f;

  bf16x8 fe[8];
#pragma unroll
  for (int ks = 0; ks < 8; ++ks) fe[ks] = *(const bf16x8*)&FeL[2 * ks + h][l31][0];

#pragma unroll
  for (int tt = 0; tt < 3; ++tt) {
    if (3 * w + tt < 8) {
      f32x16 a;
#pragma unroll
      for (int r = 0; r < 16; ++r) a[r] = 0.f;
#pragma unroll
      for (int ks = 0; ks < 8; ++ks) {
        bf16x8 wf = *(const bf16x8*)&WfeP[(((3 * w + tt) * 8 + ks) * 64 + lane) * 8];
        a = MFMA32(fe[ks], wf, a);
      }
#pragma unroll
      for (int r = 0; r < 16; ++r) accF[tt][r] = a[r];
    }
  }

  // ---- pair loop: 27 MFMA per wave per pair, in-lane max, deposit into accF
#pragma unroll
  for (int pi = 0; pi < 16; ++pi) {
    if (pi < 15) stageX((pi + 1) & 1, pi + 1);

    f32x16 a0, a1, a2;
#pragma unroll
    for (int r = 0; r < 16; ++r) { a0[r] = 0.f; a1[r] = 0.f; a2[r] = 0.f; }
#pragma unroll
    for (int ks = 0; ks < 9; ++ks) {
      bf16x8 xf = *(const bf16x8*)&Xb[pi & 1][2 * ks + h][l31][0];
      a0 = MFMA32(xf, wfm[0][ks], a0);
      a1 = MFMA32(xf, wfm[1][ks], a1);
      a2 = MFMA32(xf, wfm[2][ks], a2);
    }

    const int ra = (pi & 3) + (((pi >> 3) & 1) << 2);
    const int ha = (pi >> 2) & 1;
    const bool sel = (h == ha);
#pragma unroll
    for (int tt = 0; tt < 3; ++tt) {
      const f32x16& a = (tt == 0) ? a0 : ((tt == 1) ? a1 : a2);
      float ma = fmaxf(fmaxf(fmaxf(a[0], a[1]), fmaxf(a[2], a[3])),
                       fmaxf(fmaxf(a[4], a[5]), fmaxf(a[6], a[7])));
      float mb = fmaxf(fmaxf(fmaxf(a[8], a[9]), fmaxf(a[10], a[11])),
                       fmaxf(fmaxf(a[12], a[13]), fmaxf(a[14], a[15])));
      ma = fmaxf(ma, __shfl_xor(ma, 32));
      mb = fmaxf(mb, __shfl_xor(mb, 32));
      accF[tt][ra]     += sel ? ma : 0.f;
      accF[tt][ra + 8] += sel ? mb : 0.f;
    }
    __syncthreads();
  }

  // ---- dump R/Z/H0 logits
  const long base = (long)(g << 5) * 512;
#pragma unroll
  for (int tt = 0; tt < 3; ++tt)
#pragma unroll
    for (int r = 0; r < 16; ++r) {
      int pt = (r & 3) + ((r >> 2) << 3) + 4 * h;
      SmG[base + (long)pt * 512 + 96 * w + 32 * tt + l31] = accF[tt][r];
    }

  // ---- H1a tile (feats-only), after hot loop to limit register pressure
  {
    f32x16 a;
#pragma unroll
    for (int r = 0; r < 16; ++r) a[r] = 0.f;
#pragma unroll
    for (int ks = 0; ks < 8; ++ks) {
      bf16x8 feq = *(const bf16x8*)&FeL[2 * ks + h][l31][0];
      bf16x8 wf = *(const bf16x8*)&WfeP[(((8 + w) * 8 + ks) * 64 + lane) * 8];
      a = MFMA32(feq, wf, a);
    }
#pragma unroll
    for (int r = 0; r < 16; ++r) {
      int pt = (r & 3) + ((r >> 2) << 3) + 4 * h;
      SmG[base + (long)pt * 512 + 384 + 32 * w + l31] = a[r];
    }
  }
}

// ---------------- epilogue: gates, Pr GEMM (f32 VALU), tanh, combine, store ----------------
// block = 512 thr, 64 points; dynamic LDS: W_H1b [128][132] f32 + Pr [64][128] f32
__global__ __launch_bounds__(512) void k_epi(
    const float* __restrict__ SmG, const float* __restrict__ W_H1,
    const float* __restrict__ b_R, const float* __restrict__ b_Z,
    const float* __restrict__ b_H0, const float* __restrict__ b_H1,
    float* __restrict__ out) {
  extern __shared__ float sm[];
  float* Wl = sm;                 // [128][132]
  float* Pr = sm + 128 * 132;     // [64][128]
  const int t = threadIdx.x;
  const int blk = blockIdx.x;
  const long gp0 = (long)blk * 64;
  const int b = (int)(gp0 >> 12);
  const int nb = (int)(gp0 & 4095);

  // stage W_H1 cols 128..255 (the Pr part)
#pragma unroll
  for (int i = 0; i < 8; ++i) {
    int idx = i * 512 + t;
    int row = idx >> 5, c4 = (idx & 31) << 2;
    float4 v = *(const float4*)&W_H1[row * 256 + 128 + c4];
    *(float4*)&Wl[row * 132 + c4] = v;
  }
  // phase 1: Pr = sigmoid(R + bR) * (H0 + bH0)
  {
    int pt = t >> 3, cb = (t & 7) << 4;
    const float* row = SmG + (gp0 + pt) * 512;
#pragma unroll
    for (int ii = 0; ii < 4; ++ii) {
      int c = cb + ii * 4;
      float4 Rv = *(const float4*)&row[c];
      float4 Hv = *(const float4*)&row[256 + c];
      float4 br = *(const float4*)&b_R[c];
      float4 bh = *(const float4*)&b_H0[c];
      float4 pv;
      pv.x = (Hv.x + bh.x) / (1.f + __expf(-(Rv.x + br.x)));
      pv.y = (Hv.y + bh.y) / (1.f + __expf(-(Rv.y + br.y)));
      pv.z = (Hv.z + bh.z) / (1.f + __expf(-(Rv.z + br.z)));
      pv.w = (Hv.w + bh.w) / (1.f + __expf(-(Rv.w + br.w)));
      *(float4*)&Pr[pt * 128 + c] = pv;
    }
  }
  __syncthreads();

  // phase 2: hB[r][pt] = sum_c W_H1b[r][c] * Pr[pt][c]
  const int r = t & 127, pg = t >> 7;
  float acc[16];
#pragma unroll
  for (int p = 0; p < 16; ++p) acc[p] = 0.f;
#pragma unroll 4
  for (int c0 = 0; c0 < 32; ++c0) {
    float4 wv = *(const float4*)&Wl[r * 132 + (c0 << 2)];
#pragma unroll
    for (int p = 0; p < 16; ++p) {
      float4 pv = *(const float4*)&Pr[(pg * 16 + p) * 128 + (c0 << 2)];
      acc[p] = fmaf(wv.x, pv.x, acc[p]);
      acc[p] = fmaf(wv.y, pv.y, acc[p]);
      acc[p] = fmaf(wv.z, pv.z, acc[p]);
      acc[p] = fmaf(wv.w, pv.w, acc[p]);
    }
  }

  // phase 3: combine + store
  const float bZr = b_Z[r], bH0r = b_H0[r], bH1r = b_H1[r];
  float ov[16];
#pragma unroll
  for (int p = 0; p < 16; ++p) {
    const float* prow = SmG + (gp0 + pg * 16 + p) * 512;
    float Z   = prow[128 + r];
    float H0v = prow[256 + r];
    float Aa  = prow[384 + r];
    float gZ = 1.f / (1.f + __expf(-(Z + bZr)));
    float h0 = H0v + bH0r;
    float h1 = tanhf(Aa + acc[p] + bH1r);
    ov[p] = gZ * h0 + (1.f - gZ) * h1;
  }
  long ob = (long)(b * 128 + r) * 4096 + nb + pg * 16;
#pragma unroll
  for (int q = 0; q < 4; ++q) {
    float4 v; v.x = ov[4 * q]; v.y = ov[4 * q + 1]; v.z = ov[4 * q + 2]; v.w = ov[4 * q + 3];
    *(float4*)&out[ob + 4 * q] = v;
  }
}

extern "C" void kernel_launch(void* const* d_in, const int* in_sizes, int n_in,
                              void* d_out, int out_size, void* d_ws, size_t ws_size,
                              hipStream_t stream) {
  const float* H0  = (const float*)d_in[0];
  const float* p0  = (const float*)d_in[1];
  const float* p1  = (const float*)d_in[2];
  const float* ct  = (const float*)d_in[3];
  const float* mo  = (const float*)d_in[4];
  const float* W_R = (const float*)d_in[5];
  const float* b_R = (const float*)d_in[6];
  const float* W_Z = (const float*)d_in[7];
  const float* b_Z = (const float*)d_in[8];
  const float* W_H0 = (const float*)d_in[9];
  const float* b_H0 = (const float*)d_in[10];
  const float* W_H1 = (const float*)d_in[11];
  const float* b_H1 = (const float*)d_in[12];
  float* out = (float*)d_out;

  unsigned short* H0tb   = (unsigned short*)d_ws;
  int* nn                = (int*)((char*)d_ws + 4ull * 1024 * 1024);
  unsigned short* WmainP = (unsigned short*)((char*)d_ws + 5ull * 1024 * 1024);
  unsigned short* WfeP   = (unsigned short*)((char*)d_ws + 5ull * 1024 * 1024 + 512ull * 1024);
  float* SmG             = (float*)((char*)d_ws + 8ull * 1024 * 1024);

  k_transpose<<<8192, 256, 0, stream>>>(H0, H0tb);
  k_knn<<<4096, 256, 0, stream>>>(p0, p1, nn);
  k_prep<<<51, 256, 0, stream>>>(W_R, W_Z, W_H0, W_H1, WmainP, WfeP);
  k_mainmax<<<512, 256, 0, stream>>>(H0tb, nn, p0, p1, ct, mo,
                                     (const short*)WmainP, (const short*)WfeP, SmG);
  const int epi_lds = (128 * 132 + 64 * 128) * 4;
  hipFuncSetAttribute((const void*)k_epi, hipFuncAttributeMaxDynamicSharedMemorySize, epi_lds);
  k_epi<<<256, 512, epi_lds, stream>>>(SmG, W_H1, b_R, b_Z, b_H0, b_H1, out);
}

// Round 3
// 294.709 us; speedup vs baseline: 4.2045x; 1.5995x over previous
//
#include <hip/hip_runtime.h>
#include <math.h>

// MotionGRU: B=4, N=4096, K=16, HID=128, FEAT=128
// ws layout (bytes):
//   H0tb bf16 [4][4096][128]      @ 0        (4 MB)
//   nn    int [4][4096][16]       @ 4 MB     (1 MB)
//   WmainP bf16 frags             @ 5 MB     (110592 B)
//   WfeP   bf16 frags             @ 5.5 MB   (98304 B)
//   P0p   f32x4 [4][4096]         @ 6 MB     (256 KB)
//   SmG   f32 [16384][512]        @ 8 MB     (32 MB)

#define BIGV 1e30f

typedef __attribute__((ext_vector_type(8))) short bf16x8;
typedef __attribute__((ext_vector_type(16))) float f32x16;

#define MFMA32(a, b, c) __builtin_amdgcn_mfma_f32_32x32x16_bf16(a, b, c, 0, 0, 0)

__device__ __forceinline__ unsigned short f2bf(float x) {
  unsigned int u = __float_as_uint(x);
  unsigned int r = u + 0x7fffu + ((u >> 16) & 1u);
  return (unsigned short)(r >> 16);
}

// ---------------- transpose H0 [B,128,4096] -> H0tb bf16 [B,4096,128] ----------------
__global__ __launch_bounds__(256) void k_transpose(const float* __restrict__ H0,
                                                   unsigned short* __restrict__ H0tb) {
  __shared__ float tile[16][17];
  int blk = blockIdx.x;
  int b = blk >> 11;
  int rem = blk & 2047;
  int c0 = (rem >> 8) << 4;
  int n0 = (rem & 255) << 4;
  int tr = threadIdx.x >> 4, tc = threadIdx.x & 15;
  tile[tr][tc] = H0[((b << 7) + c0 + tr) * 4096 + n0 + tc];
  __syncthreads();
  H0tb[((b << 12) + n0 + tr) * 128 + c0 + tc] = f2bf(tile[tc][tr]);
}

// ---------------- pack candidates: P0p[b][j] = (x, y, z, |p|^2) ----------------
__global__ __launch_bounds__(256) void k_pack(const float* __restrict__ p0,
                                              float4* __restrict__ P0p) {
  int t = blockIdx.x * 256 + threadIdx.x;   // 0..16383
  int b = t >> 12, j = t & 4095;
  const float* P0 = p0 + b * 3 * 4096;
  float x = P0[j], y = P0[4096 + j], z = P0[8192 + j];
  P0p[t] = make_float4(x, y, z, x * x + y * y + z * z);
}

// ---------------- exact KNN: one wave per query, low-VGPR, u64-key extraction ----------------
__device__ __forceinline__ unsigned long long knn_key(float v, int j) {
  unsigned int u = __float_as_uint(v);
  unsigned int mask = (unsigned int)(((int)u) >> 31) | 0x80000000u;
  return ((unsigned long long)(u ^ mask) << 32) | (unsigned int)j;
}

__global__ __launch_bounds__(256) void k_knn(const float4* __restrict__ P0p,
                                             const float* __restrict__ p1,
                                             int* __restrict__ nn) {
  const int wv = threadIdx.x >> 6, lane = threadIdx.x & 63;
  const int g = (blockIdx.x << 2) + wv;
  const int b = g >> 12, m = g & 4095;
  const float* P1 = p1 + b * 3 * 4096;
  const float x1 = P1[m], y1 = P1[4096 + m], z1 = P1[8192 + m];
  const float s1 = x1 * x1 + y1 * y1 + z1 * z1;
  const float nx = -2.0f * x1, ny = -2.0f * y1, nz = -2.0f * z1;
  const float4* C = P0p + (b << 12);

  float v0 = BIGV, v1 = BIGV, v2 = BIGV, v3 = BIGV;
  int j0 = 0, j1 = 0, j2 = 0, j3 = 0;
#pragma unroll 8
  for (int t = 0; t < 64; ++t) {
    const int j = (t << 6) + lane;
    float4 c = C[j];
    // sq = s1 + s0 - 2*dot   (same math as reference)
    float sq = fmaf(nz, c.z, fmaf(ny, c.y, fmaf(nx, c.x, s1 + c.w)));
    bool c0_ = sq < v0, c1_ = sq < v1, c2_ = sq < v2, c3_ = sq < v3;
    j3 = c3_ ? (c2_ ? j2 : j) : j3;
    j2 = c2_ ? (c1_ ? j1 : j) : j2;
    j1 = c1_ ? (c0_ ? j0 : j) : j1;
    j0 = c0_ ? j : j0;
    v3 = __builtin_amdgcn_fmed3f(sq, v2, v3);
    v2 = __builtin_amdgcn_fmed3f(sq, v1, v2);
    v1 = __builtin_amdgcn_fmed3f(sq, v0, v1);
    v0 = fminf(sq, v0);
  }

  const unsigned long long INFK = ~0ull;
  unsigned long long k0 = knn_key(v0, j0), k1 = knn_key(v1, j1);
  unsigned long long k2 = knn_key(v2, j2), k3 = knn_key(v3, j3);

  unsigned long long wkey = 0;       // winner of round r kept by lane r
  unsigned long long lastk = 0;
#pragma unroll 1
  for (int r = 0; r < 16; ++r) {
    unsigned long long mk;
    if (!__any((int)(k0 == INFK))) {
      mk = k0;
    } else {
      // rare: some lane exhausted its 4 slots -> exact successor rescan for those lanes
      mk = k0;
      if (k0 == INFK) {
#pragma unroll 1
        for (int t = 0; t < 64; ++t) {
          const int j = (t << 6) + lane;
          float4 c = C[j];
          float sq = fmaf(nz, c.z, fmaf(ny, c.y, fmaf(nx, c.x, s1 + c.w)));
          unsigned long long kk = knn_key(sq, j);
          if (kk > lastk && kk < mk) mk = kk;
        }
      }
    }
    // wave-min butterfly on exact u64 keys
#pragma unroll
    for (int off = 1; off < 64; off <<= 1) {
      unsigned long long ok = __shfl_xor(mk, off);
      mk = (ok < mk) ? ok : mk;
    }
    if (lane == r) wkey = mk;
    lastk = mk;
    if (k0 == mk) { k0 = k1; k1 = k2; k2 = k3; k3 = INFK; }
  }
  const int ob = ((b << 12) + m) << 4;
  if (lane < 16) nn[ob + lane] = (int)(unsigned int)wkey;
}

// ---------------- pack weight fragments (one-time, tiny) ----------------
__global__ __launch_bounds__(256) void k_prep(const float* __restrict__ W_R,
                                              const float* __restrict__ W_Z,
                                              const float* __restrict__ W_H0,
                                              const float* __restrict__ W_H1,
                                              unsigned short* __restrict__ WmainP,
                                              unsigned short* __restrict__ WfeP) {
  int t = blockIdx.x * 256 + threadIdx.x;
  if (t < 6912) {  // 12 tiles * 9 ks * 64 lanes
    int l = t & 63;
    int f = t >> 6;
    int ks = f % 9, T = f / 9;
    int col = T * 32 + (l & 31);
    int kb = ks * 16 + ((l >> 5) << 3);
    const float* W; int stride, row;
    if (col < 128)      { W = W_R;  stride = 260; row = col; }
    else if (col < 256) { W = W_Z;  stride = 260; row = col - 128; }
    else                { W = W_H0; stride = 132; row = col - 256; }
    unsigned int u[4];
#pragma unroll
    for (int i2 = 0; i2 < 4; ++i2) {
      float a0, a1;
      int k0 = kb + 2 * i2, k1 = k0 + 1;
      a0 = (k0 < 128) ? W[row * stride + 4 + k0] : ((k0 < 132) ? W[row * stride + (k0 - 128)] : 0.f);
      a1 = (k1 < 128) ? W[row * stride + 4 + k1] : ((k1 < 132) ? W[row * stride + (k1 - 128)] : 0.f);
      u[i2] = (unsigned int)f2bf(a0) | ((unsigned int)f2bf(a1) << 16);
    }
    uint4 pk; pk.x = u[0]; pk.y = u[1]; pk.z = u[2]; pk.w = u[3];
    *(uint4*)&WmainP[t * 8] = pk;
  } else if (t < 13056) {  // 12 tiles * 8 ks * 64 lanes
    int idx = t - 6912;
    int l = idx & 63;
    int ks = (idx >> 6) & 7;
    int tid = idx >> 9;
    int kb = ks * 16 + ((l >> 5) << 3);
    unsigned int u[4];
#pragma unroll
    for (int i2 = 0; i2 < 4; ++i2) {
      int k0 = kb + 2 * i2, k1 = k0 + 1;
      float a0, a1;
      if (tid < 8) {
        int col = tid * 32 + (l & 31);
        const float* W = (col < 128) ? W_R : W_Z;
        int row = (col < 128) ? col : col - 128;
        a0 = W[row * 260 + 132 + k0];
        a1 = W[row * 260 + 132 + k1];
      } else {
        int row = (tid - 8) * 32 + (l & 31);
        a0 = W_H1[row * 256 + k0];
        a1 = W_H1[row * 256 + k1];
      }
      u[i2] = (unsigned int)f2bf(a0) | ((unsigned int)f2bf(a1) << 16);
    }
    uint4 pk; pk.x = u[0]; pk.y = u[1]; pk.z = u[2]; pk.w = u[3];
    *(uint4*)&WfeP[idx * 8] = pk;
  }
}

// ---------------- main MFMA kernel: neighbor GEMM + max + feats GEMM ----------------
__global__ __launch_bounds__(256, 2) void k_mainmax(
    const unsigned short* __restrict__ H0tb, const int* __restrict__ nn,
    const float* __restrict__ p0, const float* __restrict__ p1,
    const float* __restrict__ ct, const float* __restrict__ mo,
    const short* __restrict__ WmainP, const short* __restrict__ WfeP,
    float* __restrict__ SmG) {
  __shared__ unsigned short Xb[2][18][32][8];   // [buf][kgroup][slot][8 bf16]
  __shared__ unsigned short FeL[16][32][8];     // feats A-frags [kgroup][pt][8]

  const int t = threadIdx.x;
  const int g = blockIdx.x;
  const int b = g >> 7;
  const int n0 = (g & 127) << 5;
  const int w = t >> 6, lane = t & 63;
  const int l31 = lane & 31, h = lane >> 5;

  // persistent Wmain B-frags: wave w tiles T = 3w..3w+2, 9 k-steps each (108 VGPRs)
  bf16x8 wfm[3][9];
#pragma unroll
  for (int tt = 0; tt < 3; ++tt)
#pragma unroll
    for (int ks = 0; ks < 9; ++ks)
      wfm[tt][ks] = *(const bf16x8*)&WmainP[(((3 * w + tt) * 9 + ks) * 64 + lane) * 8];

  auto stageX = [&](int buf, int pi) {
    int s = t >> 3, c = t & 7;
    int n = n0 + pi + ((s >> 4) << 4);
    int j = nn[(((b << 12) + n) << 4) + (s & 15)];
    const uint4* src = (const uint4*)&H0tb[((b << 12) + j) * 128];
    *(uint4*)&Xb[buf][c][s][0]     = src[c];
    *(uint4*)&Xb[buf][c + 8][s][0] = src[c + 8];
    if (t < 32) {
      int s2 = t;
      int n2 = n0 + pi + ((s2 >> 4) << 4);
      int j2 = nn[(((b << 12) + n2) << 4) + (s2 & 15)];
      const float* P1b = p1 + b * 3 * 4096;
      const float* P0b = p0 + b * 3 * 4096;
      float rx = P0b[j2] - P1b[n2];
      float ry = P0b[4096 + j2] - P1b[4096 + n2];
      float rz = P0b[8192 + j2] - P1b[8192 + n2];
      float dd = sqrtf(rx * rx + ry * ry + rz * rz);
      uint4 pk;
      pk.x = (unsigned int)f2bf(rx) | ((unsigned int)f2bf(ry) << 16);
      pk.y = (unsigned int)f2bf(rz) | ((unsigned int)f2bf(dd) << 16);
      pk.z = 0u; pk.w = 0u;
      *(uint4*)&Xb[buf][16][s2][0] = pk;
      uint4 z; z.x = 0u; z.y = 0u; z.z = 0u; z.w = 0u;
      *(uint4*)&Xb[buf][17][s2][0] = z;
    }
  };

  {
    int s = t >> 3, kg = t & 7;
    int n = n0 + s;
#pragma unroll
    for (int half = 0; half < 2; ++half) {
      int kgg = kg + 8 * half;
      const float* src = half ? (mo + b * 64 * 4096) : (ct + b * 64 * 4096);
      int ch = kg * 8;
      unsigned int u[4];
#pragma unroll
      for (int i2 = 0; i2 < 4; ++i2) {
        float a0 = src[(ch + 2 * i2) * 4096 + n];
        float a1 = src[(ch + 2 * i2 + 1) * 4096 + n];
        u[i2] = (unsigned int)f2bf(a0) | ((unsigned int)f2bf(a1) << 16);
      }
      uint4 pk; pk.x = u[0]; pk.y = u[1]; pk.z = u[2]; pk.w = u[3];
      *(uint4*)&FeL[kgg][s][0] = pk;
    }
  }
  stageX(0, 0);
  __syncthreads();

  float accF[3][16];
#pragma unroll
  for (int tt = 0; tt < 3; ++tt)
#pragma unroll
    for (int r = 0; r < 16; ++r) accF[tt][r] = 0.f;

  bf16x8 fe[8];
#pragma unroll
  for (int ks = 0; ks < 8; ++ks) fe[ks] = *(const bf16x8*)&FeL[2 * ks + h][l31][0];

#pragma unroll
  for (int tt = 0; tt < 3; ++tt) {
    if (3 * w + tt < 8) {
      f32x16 a;
#pragma unroll
      for (int r = 0; r < 16; ++r) a[r] = 0.f;
#pragma unroll
      for (int ks = 0; ks < 8; ++ks) {
        bf16x8 wf = *(const bf16x8*)&WfeP[(((3 * w + tt) * 8 + ks) * 64 + lane) * 8];
        a = MFMA32(fe[ks], wf, a);
      }
#pragma unroll
      for (int r = 0; r < 16; ++r) accF[tt][r] = a[r];
    }
  }

#pragma unroll
  for (int pi = 0; pi < 16; ++pi) {
    if (pi < 15) stageX((pi + 1) & 1, pi + 1);

    f32x16 a0, a1, a2;
#pragma unroll
    for (int r = 0; r < 16; ++r) { a0[r] = 0.f; a1[r] = 0.f; a2[r] = 0.f; }
#pragma unroll
    for (int ks = 0; ks < 9; ++ks) {
      bf16x8 xf = *(const bf16x8*)&Xb[pi & 1][2 * ks + h][l31][0];
      a0 = MFMA32(xf, wfm[0][ks], a0);
      a1 = MFMA32(xf, wfm[1][ks], a1);
      a2 = MFMA32(xf, wfm[2][ks], a2);
    }

    const int ra = (pi & 3) + (((pi >> 3) & 1) << 2);
    const int ha = (pi >> 2) & 1;
    const bool sel = (h == ha);
#pragma unroll
    for (int tt = 0; tt < 3; ++tt) {
      const f32x16& a = (tt == 0) ? a0 : ((tt == 1) ? a1 : a2);
      float ma = fmaxf(fmaxf(fmaxf(a[0], a[1]), fmaxf(a[2], a[3])),
                       fmaxf(fmaxf(a[4], a[5]), fmaxf(a[6], a[7])));
      float mb = fmaxf(fmaxf(fmaxf(a[8], a[9]), fmaxf(a[10], a[11])),
                       fmaxf(fmaxf(a[12], a[13]), fmaxf(a[14], a[15])));
      ma = fmaxf(ma, __shfl_xor(ma, 32));
      mb = fmaxf(mb, __shfl_xor(mb, 32));
      accF[tt][ra]     += sel ? ma : 0.f;
      accF[tt][ra + 8] += sel ? mb : 0.f;
    }
    __syncthreads();
  }

  const long base = (long)(g << 5) * 512;
#pragma unroll
  for (int tt = 0; tt < 3; ++tt)
#pragma unroll
    for (int r = 0; r < 16; ++r) {
      int pt = (r & 3) + ((r >> 2) << 3) + 4 * h;
      SmG[base + (long)pt * 512 + 96 * w + 32 * tt + l31] = accF[tt][r];
    }

  {
    f32x16 a;
#pragma unroll
    for (int r = 0; r < 16; ++r) a[r] = 0.f;
#pragma unroll
    for (int ks = 0; ks < 8; ++ks) {
      bf16x8 feq = *(const bf16x8*)&FeL[2 * ks + h][l31][0];
      bf16x8 wf = *(const bf16x8*)&WfeP[(((8 + w) * 8 + ks) * 64 + lane) * 8];
      a = MFMA32(feq, wf, a);
    }
#pragma unroll
    for (int r = 0; r < 16; ++r) {
      int pt = (r & 3) + ((r >> 2) << 3) + 4 * h;
      SmG[base + (long)pt * 512 + 384 + 32 * w + l31] = a[r];
    }
  }
}

// ---------------- epilogue ----------------
__global__ __launch_bounds__(512) void k_epi(
    const float* __restrict__ SmG, const float* __restrict__ W_H1,
    const float* __restrict__ b_R, const float* __restrict__ b_Z,
    const float* __restrict__ b_H0, const float* __restrict__ b_H1,
    float* __restrict__ out) {
  extern __shared__ float sm[];
  float* Wl = sm;                 // [128][132]
  float* Pr = sm + 128 * 132;     // [64][128]
  const int t = threadIdx.x;
  const int blk = blockIdx.x;
  const long gp0 = (long)blk * 64;
  const int b = (int)(gp0 >> 12);
  const int nb = (int)(gp0 & 4095);

#pragma unroll
  for (int i = 0; i < 8; ++i) {
    int idx = i * 512 + t;
    int row = idx >> 5, c4 = (idx & 31) << 2;
    float4 v = *(const float4*)&W_H1[row * 256 + 128 + c4];
    *(float4*)&Wl[row * 132 + c4] = v;
  }
  {
    int pt = t >> 3, cb = (t & 7) << 4;
    const float* row = SmG + (gp0 + pt) * 512;
#pragma unroll
    for (int ii = 0; ii < 4; ++ii) {
      int c = cb + ii * 4;
      float4 Rv = *(const float4*)&row[c];
      float4 Hv = *(const float4*)&row[256 + c];
      float4 br = *(const float4*)&b_R[c];
      float4 bh = *(const float4*)&b_H0[c];
      float4 pv;
      pv.x = (Hv.x + bh.x) / (1.f + __expf(-(Rv.x + br.x)));
      pv.y = (Hv.y + bh.y) / (1.f + __expf(-(Rv.y + br.y)));
      pv.z = (Hv.z + bh.z) / (1.f + __expf(-(Rv.z + br.z)));
      pv.w = (Hv.w + bh.w) / (1.f + __expf(-(Rv.w + br.w)));
      *(float4*)&Pr[pt * 128 + c] = pv;
    }
  }
  __syncthreads();

  const int r = t & 127, pg = t >> 7;
  float acc[16];
#pragma unroll
  for (int p = 0; p < 16; ++p) acc[p] = 0.f;
#pragma unroll 4
  for (int c0 = 0; c0 < 32; ++c0) {
    float4 wv = *(const float4*)&Wl[r * 132 + (c0 << 2)];
#pragma unroll
    for (int p = 0; p < 16; ++p) {
      float4 pv = *(const float4*)&Pr[(pg * 16 + p) * 128 + (c0 << 2)];
      acc[p] = fmaf(wv.x, pv.x, acc[p]);
      acc[p] = fmaf(wv.y, pv.y, acc[p]);
      acc[p] = fmaf(wv.z, pv.z, acc[p]);
      acc[p] = fmaf(wv.w, pv.w, acc[p]);
    }
  }

  const float bZr = b_Z[r], bH0r = b_H0[r], bH1r = b_H1[r];
  float ov[16];
#pragma unroll
  for (int p = 0; p < 16; ++p) {
    const float* prow = SmG + (gp0 + pg * 16 + p) * 512;
    float Z   = prow[128 + r];
    float H0v = prow[256 + r];
    float Aa  = prow[384 + r];
    float gZ = 1.f / (1.f + __expf(-(Z + bZr)));
    float h0 = H0v + bH0r;
    float h1 = tanhf(Aa + acc[p] + bH1r);
    ov[p] = gZ * h0 + (1.f - gZ) * h1;
  }
  long ob = (long)(b * 128 + r) * 4096 + nb + pg * 16;
#pragma unroll
  for (int q = 0; q < 4; ++q) {
    float4 v; v.x = ov[4 * q]; v.y = ov[4 * q + 1]; v.z = ov[4 * q + 2]; v.w = ov[4 * q + 3];
    *(float4*)&out[ob + 4 * q] = v;
  }
}

extern "C" void kernel_launch(void* const* d_in, const int* in_sizes, int n_in,
                              void* d_out, int out_size, void* d_ws, size_t ws_size,
                              hipStream_t stream) {
  const float* H0  = (const float*)d_in[0];
  const float* p0  = (const float*)d_in[1];
  const float* p1  = (const float*)d_in[2];
  const float* ct  = (const float*)d_in[3];
  const float* mo  = (const float*)d_in[4];
  const float* W_R = (const float*)d_in[5];
  const float* b_R = (const float*)d_in[6];
  const float* W_Z = (const float*)d_in[7];
  const float* b_Z = (const float*)d_in[8];
  const float* W_H0 = (const float*)d_in[9];
  const float* b_H0 = (const float*)d_in[10];
  const float* W_H1 = (const float*)d_in[11];
  const float* b_H1 = (const float*)d_in[12];
  float* out = (float*)d_out;

  unsigned short* H0tb   = (unsigned short*)d_ws;
  int* nn                = (int*)((char*)d_ws + 4ull * 1024 * 1024);
  unsigned short* WmainP = (unsigned short*)((char*)d_ws + 5ull * 1024 * 1024);
  unsigned short* WfeP   = (unsigned short*)((char*)d_ws + 5ull * 1024 * 1024 + 512ull * 1024);
  float4* P0p            = (float4*)((char*)d_ws + 6ull * 1024 * 1024);
  float* SmG             = (float*)((char*)d_ws + 8ull * 1024 * 1024);

  k_transpose<<<8192, 256, 0, stream>>>(H0, H0tb);
  k_pack<<<64, 256, 0, stream>>>(p0, P0p);
  k_knn<<<4096, 256, 0, stream>>>(P0p, p1, nn);
  k_prep<<<51, 256, 0, stream>>>(W_R, W_Z, W_H0, W_H1, WmainP, WfeP);
  k_mainmax<<<512, 256, 0, stream>>>(H0tb, nn, p0, p1, ct, mo,
                                     (const short*)WmainP, (const short*)WfeP, SmG);
  const int epi_lds = (128 * 132 + 64 * 128) * 4;
  hipFuncSetAttribute((const void*)k_epi, hipFuncAttributeMaxDynamicSharedMemorySize, epi_lds);
  k_epi<<<256, 512, epi_lds, stream>>>(SmG, W_H1, b_R, b_Z, b_H0, b_H1, out);
}